// Round 28
// baseline (1113.902 us; speedup 1.0000x reference)
//
#include <hip/hip_runtime.h>
#include <math.h>
#include <float.h>

#define DEV __device__ __forceinline__

#define BB 8
#define TT 24000
#define TD 23989
#define NZ 2000
#define ROWS 16000
#define NE 8192
#define NCG 8

typedef __attribute__((ext_vector_type(8))) short bf16x8;
typedef __attribute__((ext_vector_type(4))) float f32x4;

// ---------------- static device storage ----------------
__device__ double g_st[640];
__device__ double g_misc[2];
__device__ float  g_e2[NE];
__device__ float  g_avg[NE];
__device__ float  g_z2[ROWS];
__device__ float  g_rdm[ROWS];
__device__ int    g_rix[ROWS];
__device__ float  g_ob[256 * 64];
__device__ float  g_pmd[ROWS * NCG];
__device__ int    g_pmi[ROWS * NCG];
__device__ int    g_pcc[ROWS * NCG];
__device__ float2 g_cand[ROWS * 256];
__device__ unsigned short g_zbh[ROWS * 64], g_zbl[ROWS * 64];
__device__ unsigned short g_ebh[NE * 64],  g_ebl[NE * 64];
__device__ float  g_s1[16], g_sh1[16];
__device__ float  g_s2[32], g_sh2[32];
__device__ float  g_sd1[64], g_shd1[64];
__device__ float  g_w2f[2560];
__device__ float  g_b2f[32];
__device__ float  g_w3f[64 * 32 * 25];
__device__ float  g_b3f[64];
__device__ float  g_dw2f[64 * 5 * 64];
__device__ float  g_db2f[64];
__device__ float  g_dw1t[64 * 64 * 25];
__device__ float  g_zbn[ROWS * 64];
__device__ double g_zbnd[ROWS * 64];
__device__ float  g_zq[BB * 64 * NZ];
__device__ float  g_y1[BB * 16 * TT];
__device__ float  g_zpre[BB * 64 * NZ];
__device__ float  g_yd1[BB * 64 * TD];
__device__ float  g_y2[BB * 32 * TT];
__device__ float  g_yd2[BB * 64 * TD];

DEV float wsum(float v){
  #pragma unroll
  for (int o = 32; o; o >>= 1) v += __shfl_xor(v, o, 64);
  return v;
}
DEV int clampc(int c){ return c < 0 ? 0 : (c > NE - 1 ? NE - 1 : c); }
DEV float bss(unsigned short s){ union { unsigned u; float f; } v; v.u = ((unsigned)s) << 16; return v.f; }
DEV unsigned short f2bs(float f){
  union { float f; unsigned u; } v; v.f = f;
  unsigned r = (v.u + 0x7FFF + ((v.u >> 16) & 1)) >> 16;
  return (unsigned short)r;
}

__global__ void k_zero(){
  int i = blockIdx.x * 256 + threadIdx.x;
  if (i < 640) g_st[i] = 0.0;
  if (i < 2) g_misc[i] = 0.0;
  if (i < NE) g_avg[i] = 0.f;
}

// ---------------- embed prep: |e|^2 + bf16 split ----------------
__global__ void k_embprep(const float* __restrict__ embed){
  int gt = blockIdx.x * 256 + threadIdx.x;
  int gs = gridDim.x * 256;
  for (int i = gt; i < NE * 64; i += gs){
    float v = embed[i];
    unsigned short h = f2bs(v);
    g_ebh[i] = h;
    g_ebl[i] = f2bs(v - bss(h));
  }
  for (int c = gt; c < NE; c += gs){
    float s = 0.f;
    for (int j = 0; j < 64; j++){ float v = embed[c * 64 + j]; s += v * v; }
    g_e2[c] = s;
  }
}

// ---------------- z bf16 split (after zbn) ----------------
__global__ void k_zsplit(){
  int i = blockIdx.x * 256 + threadIdx.x;
  if (i < ROWS * 64){
    float v = g_zbn[i];
    unsigned short h = f2bs(v);
    g_zbh[i] = h;
    g_zbl[i] = f2bs(v - bss(h));
  }
}

// ---------------- conv1: silu + stats ----------------
__global__ void k_conv1(const float* __restrict__ x, const float* __restrict__ w1,
                        const float* __restrict__ b1){
  int b = blockIdx.y, t0 = blockIdx.x * 256, tid = threadIdx.x;
  __shared__ float xs[260], wl[80], bl[16], sacc[16], qacc[16];
  if (tid < 80) wl[tid] = w1[tid];
  if (tid < 16){ bl[tid] = b1[tid]; sacc[tid] = 0.f; qacc[tid] = 0.f; }
  for (int i = tid; i < 260; i += 256){ int g = t0 - 2 + i; xs[i] = ((unsigned)g < TT) ? x[b * TT + g] : 0.f; }
  __syncthreads();
  int t = t0 + tid;
  bool ok = t < TT;
  float xv[5];
  #pragma unroll
  for (int k = 0; k < 5; k++) xv[k] = xs[tid + k];
  float out[16];
  #pragma unroll
  for (int c = 0; c < 16; c++){
    float a = bl[c];
    #pragma unroll
    for (int k = 0; k < 5; k++) a += wl[c * 5 + k] * xv[k];
    float o = ok ? a / (1.f + expf(-a)) : 0.f;
    out[c] = o;
    if (ok) g_y1[(b * 16 + c) * TT + t] = o;
  }
  int lane = tid & 63;
  #pragma unroll
  for (int c = 0; c < 16; c++){
    float s = wsum(out[c]);
    float q = wsum(out[c] * out[c]);
    if (lane == 0){ atomicAdd(&sacc[c], s); atomicAdd(&qacc[c], q); }
  }
  __syncthreads();
  if (tid < 16){ atomicAdd(&g_st[tid * 2], (double)sacc[tid]); atomicAdd(&g_st[tid * 2 + 1], (double)qacc[tid]); }
}

// ---------------- bn1 factors + raw w2 transpose ----------------
__global__ void k_fold2(const float* __restrict__ g1, const float* __restrict__ be1,
                        const float* __restrict__ w2, const float* __restrict__ b2){
  int tid = threadIdx.x;
  if (blockIdx.x == 0 && tid < 16){
    double m = g_st[tid * 2] / 192000.0, v = g_st[tid * 2 + 1] / 192000.0 - m * m;
    float s = g1[tid] / sqrtf((float)v + 1e-5f);
    g_s1[tid] = s; g_sh1[tid] = be1[tid] - (float)m * s;
  }
  if (blockIdx.x == 0 && tid < 32) g_b2f[tid] = b2[tid];
  int gt = blockIdx.x * 256 + tid;
  for (int i = gt; i < 2560; i += 8 * 256){
    int co = i & 31, r = i >> 5, k = r % 5, ci = r / 5;
    g_w2f[i] = w2[(co * 16 + ci) * 5 + k];
  }
}

// ---------------- conv2: 8co/wave x 4t/lane, BN at stage-in, silu, stats ----------------
__global__ void __launch_bounds__(256) k_conv2(){
  int b = blockIdx.y, t0 = blockIdx.x * 256, tid = threadIdx.x;
  __shared__ float xs[16][260];
  __shared__ float sacc[32], qacc[32];
  __shared__ float s1l[16], sh1l[16];
  int lane = tid & 63, wv = tid >> 6;
  int cb = wv * 8;
  if (tid < 32){ sacc[tid] = 0.f; qacc[tid] = 0.f; }
  if (tid < 16){ s1l[tid] = g_s1[tid]; sh1l[tid] = g_sh1[tid]; }
  __syncthreads();
  for (int i = tid; i < 16 * 260; i += 256){
    int ci = i / 260, tt = i - ci * 260, g = t0 - 2 + tt;
    xs[ci][tt] = ((unsigned)g < TT) ? (s1l[ci] * g_y1[(b * 16 + ci) * TT + g] + sh1l[ci]) : 0.f;
  }
  __syncthreads();
  float acc[4][8];
  #pragma unroll
  for (int j = 0; j < 4; j++)
    #pragma unroll
    for (int i = 0; i < 8; i++) acc[j][i] = g_b2f[cb + i];
  for (int ci = 0; ci < 16; ci++){
    #pragma unroll
    for (int k = 0; k < 5; k++){
      const float4* wp = (const float4*)(g_w2f + (ci * 5 + k) * 32 + cb);
      float4 w0 = wp[0], w1v = wp[1];
      float wr[8] = { w0.x, w0.y, w0.z, w0.w, w1v.x, w1v.y, w1v.z, w1v.w };
      #pragma unroll
      for (int j = 0; j < 4; j++){
        float xv = xs[ci][lane + 64 * j + k];
        #pragma unroll
        for (int i = 0; i < 8; i++) acc[j][i] += wr[i] * xv;
      }
    }
  }
  #pragma unroll
  for (int i = 0; i < 8; i++){
    int co = cb + i;
    float s = 0.f, q = 0.f;
    #pragma unroll
    for (int j = 0; j < 4; j++){
      int t = t0 + lane + 64 * j;
      bool ok = t < TT;
      float a = acc[j][i];
      float o = ok ? a / (1.f + expf(-a)) : 0.f;
      if (ok) g_y2[(b * 32 + co) * TT + t] = o;
      s += o; q += o * o;
    }
    s = wsum(s); q = wsum(q);
    if (lane == 0){ atomicAdd(&sacc[co], s); atomicAdd(&qacc[co], q); }
  }
  __syncthreads();
  if (tid < 32){ atomicAdd(&g_st[128 + tid * 2], (double)sacc[tid]); atomicAdd(&g_st[128 + tid * 2 + 1], (double)qacc[tid]); }
}

// ---------------- bn2 factors + raw w3 transpose ----------------
__global__ void k_fold3(const float* __restrict__ g2, const float* __restrict__ be2,
                        const float* __restrict__ w3, const float* __restrict__ b3){
  int tid = threadIdx.x;
  if (blockIdx.x == 0 && tid < 32){
    double m = g_st[128 + tid * 2] / 192000.0, v = g_st[128 + tid * 2 + 1] / 192000.0 - m * m;
    float s = g2[tid] / sqrtf((float)v + 1e-5f);
    g_s2[tid] = s; g_sh2[tid] = be2[tid] - (float)m * s;
  }
  if (blockIdx.x == 0 && tid >= 64 && tid < 128) g_b3f[tid - 64] = b3[tid - 64];
  int gt = blockIdx.x * 256 + tid;
  for (int i = gt; i < 64 * 32 * 25; i += 64 * 256){
    int co = i & 63, r = i >> 6, k = r % 25, ci = r / 25;
    g_w3f[i] = w3[(co * 32 + ci) * 25 + k];
  }
}

// ---------------- conv3: 16co/wave, lane=(t32,ci-half), shfl reduce, tanh ----------------
__global__ void __launch_bounds__(256) k_conv3(){
  __shared__ float xs[32][400];
  __shared__ float s2l[32], sh2l[32];
  int tid = threadIdx.x, b = blockIdx.y, t0 = blockIdx.x * 32;
  int lane = tid & 63, wv = tid >> 6;
  int cb = wv * 16;
  int tl = lane & 31, h = lane >> 5;
  if (tid < 32){ s2l[tid] = g_s2[tid]; sh2l[tid] = g_sh2[tid]; }
  __syncthreads();
  int p0 = t0 * 12 - 12;
  for (int i = tid; i < 32 * 397; i += 256){
    int ci = i / 397, pp = i - ci * 397, g = p0 + pp;
    xs[ci][pp] = ((unsigned)g < TT) ? (s2l[ci] * g_y2[(b * 32 + ci) * TT + g] + sh2l[ci]) : 0.f;
  }
  __syncthreads();
  float acc[16];
  #pragma unroll
  for (int i = 0; i < 16; i++) acc[i] = 0.f;
  for (int cii = 0; cii < 16; cii++){
    int ci = h * 16 + cii;
    #pragma unroll
    for (int k = 0; k < 25; k++){
      float xv = xs[ci][tl * 12 + k];
      const float4* wp = (const float4*)(g_w3f + (ci * 25 + k) * 64 + cb);
      float4 a0 = wp[0], a1 = wp[1], a2 = wp[2], a3 = wp[3];
      acc[0] += a0.x * xv; acc[1] += a0.y * xv; acc[2] += a0.z * xv; acc[3] += a0.w * xv;
      acc[4] += a1.x * xv; acc[5] += a1.y * xv; acc[6] += a1.z * xv; acc[7] += a1.w * xv;
      acc[8] += a2.x * xv; acc[9] += a2.y * xv; acc[10] += a2.z * xv; acc[11] += a2.w * xv;
      acc[12] += a3.x * xv; acc[13] += a3.y * xv; acc[14] += a3.z * xv; acc[15] += a3.w * xv;
    }
  }
  #pragma unroll
  for (int i = 0; i < 16; i++) acc[i] += __shfl_xor(acc[i], 32, 64);
  int t = t0 + tl;
  if (h == 0 && t < NZ){
    #pragma unroll
    for (int i = 0; i < 16; i++)
      g_zpre[(b * 64 + cb + i) * NZ + t] = tanhf(acc[i] + g_b3f[cb + i]);
  }
}

// ---------------- per-channel stats (zpre only) ----------------
__global__ void k_stats(int which, int L, int stoff){
  const float* p = (which == 0) ? g_zpre : (which == 1) ? g_yd1 : g_yd2;
  int co = blockIdx.y, t0 = blockIdx.x * 256, tid = threadIdx.x;
  int t = t0 + tid;
  float s = 0.f, q = 0.f;
  if (t < L){
    for (int b = 0; b < BB; b++){ float v = p[(b * 64 + co) * L + t]; s += v; q += v * v; }
  }
  s = wsum(s); q = wsum(q);
  __shared__ float sa[4], qa[4];
  int w = tid >> 6, lane = tid & 63;
  if (lane == 0){ sa[w] = s; qa[w] = q; }
  __syncthreads();
  if (tid == 0){
    atomicAdd(&g_st[stoff + co * 2], (double)(sa[0] + sa[1] + sa[2] + sa[3]));
    atomicAdd(&g_st[stoff + co * 2 + 1], (double)(qa[0] + qa[1] + qa[2] + qa[3]));
  }
}

// ---------------- bn3 apply + transpose rows + |z|^2 (+f64 copy) ----------------
__global__ void k_zbn(const float* __restrict__ g3, const float* __restrict__ be3){
  __shared__ float tile[64][65];
  __shared__ float s3[64], sh3[64];
  __shared__ double s3d[64], sh3d[64];
  int tid = threadIdx.x, b = blockIdx.y, n0 = blockIdx.x * 64;
  if (tid < 64){
    double m = g_st[256 + tid * 2] / 16000.0, v = g_st[256 + tid * 2 + 1] / 16000.0 - m * m;
    double sd = (double)g3[tid] / sqrt(v + 1e-5);
    double shd = (double)be3[tid] - m * sd;
    s3d[tid] = sd; sh3d[tid] = shd;
    s3[tid] = (float)sd; sh3[tid] = (float)shd;
  }
  __syncthreads();
  for (int i = tid; i < 64 * 64; i += 256){
    int c = i >> 6, nn = i & 63, n = n0 + nn;
    tile[c][nn] = (n < NZ) ? (s3[c] * g_zpre[(b * 64 + c) * NZ + n] + sh3[c]) : 0.f;
  }
  __syncthreads();
  int lane = tid & 63;
  for (int it = 0; it < 16; ++it){
    int nn = (tid >> 6) + it * 4;
    int n = n0 + nn, c = lane;
    if (n < NZ){
      float v = tile[c][nn];
      int row = b * NZ + n;
      g_zbn[row * 64 + c] = v;
      g_zbnd[row * 64 + c] = s3d[c] * (double)g_zpre[(b * 64 + c) * NZ + n] + sh3d[c];
      float s = wsum(v * v);
      if (lane == 0) g_z2[row] = s;
    }
  }
}

// ---------------- VQ pass 1: split-bf16 MFMA distance scan (per-chunk thr reduce) ----------------
__global__ void __launch_bounds__(256) k_vq1(){
  __shared__ unsigned short bsh[64 * 72];
  __shared__ unsigned short bsl[64 * 72];
  __shared__ float2 ring[64][16];
  __shared__ int cnt[64];
  int tid = threadIdx.x, lane = tid & 63, w = tid >> 6;
  int q = lane >> 4, col = lane & 15;
  int rowbase = blockIdx.x * 64 + w * 16;
  int cbase = blockIdx.y * 1024;
  int grp = blockIdx.y;
  if (tid < 64) cnt[tid] = 0;
  #pragma unroll
  for (int i = 0; i < 4; i++)
    ring[w * 16 + (lane & 15)][(lane >> 4) * 4 + i] = make_float2(FLT_MAX, __int_as_float(NE - 1));
  bf16x8 ah0, ah1, al0, al1;
  {
    const unsigned short* zh = g_zbh + (rowbase + col) * 64;
    const unsigned short* zl = g_zbl + (rowbase + col) * 64;
    ah0 = *(const bf16x8*)(zh + q * 8);
    ah1 = *(const bf16x8*)(zh + 32 + q * 8);
    al0 = *(const bf16x8*)(zl + q * 8);
    al1 = *(const bf16x8*)(zl + 32 + q * 8);
  }
  float z2r[4];
  #pragma unroll
  for (int r = 0; r < 4; r++) z2r[r] = g_z2[rowbase + q * 4 + r];
  float thr[4], lmin[4]; int lamc[4];
  #pragma unroll
  for (int r = 0; r < 4; r++){ thr[r] = FLT_MAX; lmin[r] = FLT_MAX; lamc[r] = NE - 1; }
  float runmin[4] = {FLT_MAX, FLT_MAX, FLT_MAX, FLT_MAX};
  for (int ch = 0; ch < 16; ++ch){
    __syncthreads();
    {
      int cl = tid >> 2, seg = tid & 3;
      int cglob = cbase + ch * 64 + cl;
      *(int4*)&bsh[cl * 72 + seg * 16]     = *(const int4*)(g_ebh + cglob * 64 + seg * 16);
      *(int4*)&bsh[cl * 72 + seg * 16 + 8] = *(const int4*)(g_ebh + cglob * 64 + seg * 16 + 8);
      *(int4*)&bsl[cl * 72 + seg * 16]     = *(const int4*)(g_ebl + cglob * 64 + seg * 16);
      *(int4*)&bsl[cl * 72 + seg * 16 + 8] = *(const int4*)(g_ebl + cglob * 64 + seg * 16 + 8);
    }
    __syncthreads();
    float d2s[4][4];
    float tmin[4] = {FLT_MAX, FLT_MAX, FLT_MAX, FLT_MAX};
    #pragma unroll
    for (int t = 0; t < 4; t++){
      int ct = cbase + ch * 64 + t * 16;
      const unsigned short* bhp = &bsh[(t * 16 + col) * 72];
      const unsigned short* blp = &bsl[(t * 16 + col) * 72];
      bf16x8 bh0 = *(const bf16x8*)(bhp + q * 8);
      bf16x8 bh1 = *(const bf16x8*)(bhp + 32 + q * 8);
      bf16x8 bl0 = *(const bf16x8*)(blp + q * 8);
      bf16x8 bl1 = *(const bf16x8*)(blp + 32 + q * 8);
      f32x4 acc = {0.f, 0.f, 0.f, 0.f};
      acc = __builtin_amdgcn_mfma_f32_16x16x32_bf16(al0, bh0, acc, 0, 0, 0);
      acc = __builtin_amdgcn_mfma_f32_16x16x32_bf16(al1, bh1, acc, 0, 0, 0);
      acc = __builtin_amdgcn_mfma_f32_16x16x32_bf16(ah0, bl0, acc, 0, 0, 0);
      acc = __builtin_amdgcn_mfma_f32_16x16x32_bf16(ah1, bl1, acc, 0, 0, 0);
      acc = __builtin_amdgcn_mfma_f32_16x16x32_bf16(ah0, bh0, acc, 0, 0, 0);
      acc = __builtin_amdgcn_mfma_f32_16x16x32_bf16(ah1, bh1, acc, 0, 0, 0);
      float e2c = g_e2[ct + col];
      #pragma unroll
      for (int r = 0; r < 4; r++){
        float d = z2r[r] + e2c - 2.f * acc[r];
        d2s[t][r] = d;
        if (d < lmin[r]){ lmin[r] = d; lamc[r] = ct + col; }
        tmin[r] = fminf(tmin[r], d);
      }
    }
    #pragma unroll
    for (int r = 0; r < 4; r++){
      float m = tmin[r];
      m = fminf(m, __shfl_xor(m, 1, 64));
      m = fminf(m, __shfl_xor(m, 2, 64));
      m = fminf(m, __shfl_xor(m, 4, 64));
      m = fminf(m, __shfl_xor(m, 8, 64));
      if (m < runmin[r]){
        runmin[r] = m;
        thr[r] = m + 0.71f * sqrtf(fmaxf(m, 0.f)) + 0.13f;
      }
    }
    #pragma unroll
    for (int t = 0; t < 4; t++){
      int ct = cbase + ch * 64 + t * 16;
      bool any = false;
      #pragma unroll
      for (int r = 0; r < 4; r++) if (d2s[t][r] < thr[r]) any = true;
      if (__ballot(any)){
        #pragma unroll
        for (int r = 0; r < 4; r++){
          if (d2s[t][r] < thr[r]){
            int lr = w * 16 + q * 4 + r;
            int s = atomicAdd(&cnt[lr], 1) & 15;
            ring[lr][s] = make_float2(sqrtf(fmaxf(d2s[t][r], 1e-12f)), __int_as_float(ct + col));
          }
        }
      }
    }
  }
  __syncthreads();
  #pragma unroll
  for (int r = 0; r < 4; r++){
    float m = lmin[r]; int c = lamc[r];
    #pragma unroll
    for (int o = 1; o <= 8; o <<= 1){
      float om = __shfl_xor(m, o, 64);
      int oc = __shfl_xor(c, o, 64);
      if (om < m || (om == m && oc < c)){ m = om; c = oc; }
    }
    if (col == 0){
      int gr = rowbase + q * 4 + r;
      g_pmd[gr * NCG + grp] = m;
      g_pmi[gr * NCG + grp] = c;
    }
  }
  if (lane < 16){
    int lr = w * 16 + lane;
    g_pcc[(rowbase + lane) * NCG + grp] = cnt[lr];
  }
  #pragma unroll
  for (int i = 0; i < 4; i++){
    int idx = lane * 4 + i;
    int lr = idx >> 4, s = idx & 15;
    g_cand[(rowbase + lr) * 256 + grp * 16 + s] = ring[w * 16 + lr][s];
  }
}

__global__ void k_vq1b(){
  int row = blockIdx.x * 256 + threadIdx.x;
  if (row >= ROWS) return;
  float best = FLT_MAX; int bi = NE - 1;
  for (int cg = 0; cg < NCG; ++cg){
    float d = g_pmd[row * NCG + cg]; int i = g_pmi[row * NCG + cg];
    if (d < best || (d == best && i < bi)){ best = d; bi = i; }
  }
  g_rdm[row] = sqrtf(fmaxf(best, 1e-12f));
  g_rix[row] = bi;
}

// ---------------- VQ pass 3: wave-cooperative f64 re-rank (lane = dim) + exact softmax ----------------
// grid.x * 4 == ROWS exactly (4000 * 4 = 16000): no early-return divergence.
__global__ void __launch_bounds__(256) k_vq3(const float* __restrict__ embed,
                                             float* __restrict__ outIdx){
  __shared__ int   ccode[4][144];
  __shared__ float cdst[4][144];
  __shared__ int   cn[4];
  int w = threadIdx.x >> 6, lane = threadIdx.x & 63;
  int row = blockIdx.x * 4 + w;
  float dmin = g_rdm[row];
  int seedc = clampc(g_rix[row]);
  if (lane == 0){ cn[w] = 0; ccode[w][0] = seedc; }
  __syncthreads();
  if (lane == 0) cn[w] = 1;
  int grp = lane & 7;
  int sub = lane >> 3;
  int cnt = g_pcc[row * NCG + grp]; if (cnt > 16) cnt = 16;
  int s0 = sub * 2, s1 = s0 + 2; if (s1 > cnt) s1 = cnt;
  for (int s = s0; s < s1; ++s){
    float2 cd = g_cand[row * 256 + grp * 16 + s];
    float dist = cd.x; int c = clampc(__float_as_int(cd.y));
    if (dist <= dmin + 0.353f && c != seedc){
      int i = atomicAdd(&cn[w], 1);
      ccode[w][i] = c;
    }
  }
  __syncthreads();
  int n = cn[w];
  double zdl = g_zbnd[row * 64 + lane];
  double bd = DBL_MAX; int bc = NE - 1;
  for (int i = 0; i < n; i++){
    int c = ccode[w][i];
    double diff = zdl - (double)embed[c * 64 + lane];
    double d = diff * diff;
    #pragma unroll
    for (int o = 32; o; o >>= 1) d += __shfl_xor(d, o, 64);
    if (lane == 0) cdst[w][i] = (float)d;
    if (d < bd || (d == bd && c < bc)){ bd = d; bc = c; }
  }
  __syncthreads();
  float dminE = (float)sqrt(bd);
  float Zp = 0.f;
  for (int i = lane; i < n; i += 64)
    Zp += expf(-100.f * (sqrtf(cdst[w][i]) - dminE));
  float Z = fmaxf(wsum(Zp), 1e-30f);
  if (lane == 0){
    g_rix[row] = bc;
    outIdx[row] = (float)bc;
    atomicAdd(&g_misc[0], bd);
  }
  for (int i = lane; i < n; i += 64)
    atomicAdd(&g_avg[ccode[w][i]], expf(-100.f * (sqrtf(cdst[w][i]) - dminE)) / Z);
}

__global__ void k_orthoprep(const float* __restrict__ embed, const int* __restrict__ oidx){
  int tid = threadIdx.x;
  int c = clampc(oidx[tid]);
  float s = 0.f;
  for (int j = 0; j < 64; j++){ float v = embed[c * 64 + j]; s += v * v; }
  float r = 1.f / sqrtf(s + 1e-12f);
  for (int j = 0; j < 64; j++) g_ob[tid * 64 + j] = embed[c * 64 + j] * r;
}

__global__ void k_ortho(){
  int w = threadIdx.x >> 6, lane = threadIdx.x & 63;
  int i = blockIdx.x * 4 + w;
  float acc = 0.f;
  for (int j = lane; j < 256; j += 64){
    float d = 0.f;
    for (int k = 0; k < 64; k++) d += g_ob[i * 64 + k] * g_ob[j * 64 + k];
    acc += d * d;
  }
  acc = wsum(acc);
  if (lane == 0) atomicAdd(&g_misc[1], (double)acc);
}

__global__ void k_div(float* __restrict__ outS){
  int tid = threadIdx.x;
  double part = 0.0;
  for (int c = tid; c < NE; c += 256){
    double p = (double)g_avg[c] / 16000.0;
    double pc = p < 1e-30 ? 1e-30 : p;
    part += p * log(pc);
  }
  __shared__ double red[256];
  red[tid] = part; __syncthreads();
  for (int o = 128; o; o >>= 1){ if (tid < o) red[tid] += red[tid + o]; __syncthreads(); }
  if (tid == 0){
    double diversity = red[0];
    double commit = g_misc[0] / (double)(ROWS * 64);
    double ortho = g_misc[1] / 65536.0 - 1.0 / 256.0;
    double loss = commit + diversity + ortho;
    outS[0] = (float)loss;
    outS[1] = (float)commit;
    outS[2] = (float)diversity;
    outS[3] = (float)ortho;
  }
}

__global__ void k_zq(const float* __restrict__ embed){
  __shared__ float tile[64][65];
  int tid = threadIdx.x, b = blockIdx.y, n0 = blockIdx.x * 64;
  for (int i = tid; i < 64 * 64; i += 256){
    int nn = i >> 6, c = i & 63;
    int n = n0 + nn;
    int code = (n < NZ) ? clampc(g_rix[b * NZ + n]) : 0;
    tile[c][nn] = embed[code * 64 + c];
  }
  __syncthreads();
  for (int i = tid; i < 64 * 64; i += 256){
    int c = i >> 6, nn = i & 63;
    int n = n0 + nn;
    if (n < NZ) g_zq[(b * 64 + c) * NZ + n] = tile[c][nn];
  }
}

__global__ void k_folddw1(const float* __restrict__ dw1){
  int gt = blockIdx.x * 256 + threadIdx.x;
  for (int i = gt; i < 64 * 64 * 25; i += 100 * 256){
    int co = i & 63, r = i >> 6, k = r % 25, ci = r / 25;
    g_dw1t[i] = dw1[(ci * 64 + co) * 25 + (24 - k)];
  }
}

// ---------------- dconv1: LDS weight staging (4 ch/block, 1 ch/wave), static acc ----------------
__global__ void __launch_bounds__(256) k_dconv1(){
  __shared__ float xsd[64][68];
  __shared__ float wsh[64 * 25 * 4];
  __shared__ float sacc[4], qacc[4];
  int tid = threadIdx.x, b = blockIdx.y;
  int cb = blockIdx.z * 4;
  int t0 = blockIdx.x * 768;
  int nb = t0 / 12 - 1;
  if (tid < 4){ sacc[tid] = 0.f; qacc[tid] = 0.f; }
  for (int i = tid; i < 64 * 67; i += 256){
    int ci = i / 67, nl = i - ci * 67, n = nb + nl;
    xsd[ci][nl] = ((unsigned)n < NZ) ? g_zq[(b * 64 + ci) * NZ + n] : 0.f;
  }
  for (int i = tid; i < 64 * 25 * 4; i += 256){
    int r = i >> 2, c = i & 3;
    wsh[i] = g_dw1t[r * 64 + cb + c];
  }
  __syncthreads();
  int w = tid >> 6, lane = tid & 63;
  float acc[12];
  #pragma unroll
  for (int p = 0; p < 12; p++) acc[p] = 0.f;
  for (int ci = 0; ci < 64; ci++){
    float xmA = xsd[ci][lane];
    float xm0 = xsd[ci][lane + 1];
    float xmB = xsd[ci][lane + 2];
    const float* wci = wsh + ci * 100 + w;
    acc[0] += wci[0] * xmA;
    acc[0] += wci[12 * 4] * xm0;
    acc[0] += wci[24 * 4] * xmB;
    #pragma unroll
    for (int p = 1; p < 12; p++){
      acc[p] += wci[(12 - p) * 4] * xm0;
      acc[p] += wci[(24 - p) * 4] * xmB;
    }
  }
  bool full = (t0 + 768 <= TD);
  {
    float o[12];
    float s = 0.f, q = 0.f;
    #pragma unroll
    for (int p = 0; p < 12; p++){
      int t = t0 + lane * 12 + p;
      float a = acc[p];
      float v = (t < TD) ? a / (1.f + expf(-a)) : 0.f;
      o[p] = v; s += v; q += v * v;
    }
    float* dst = &g_yd1[(b * 64 + cb + w) * TD + t0 + lane * 12];
    if (full){
      ((float4*)dst)[0] = make_float4(o[0], o[1], o[2], o[3]);
      ((float4*)dst)[1] = make_float4(o[4], o[5], o[6], o[7]);
      ((float4*)dst)[2] = make_float4(o[8], o[9], o[10], o[11]);
    } else {
      #pragma unroll
      for (int p = 0; p < 12; p++){
        int t = t0 + lane * 12 + p;
        if (t < TD) dst[p] = o[p];
      }
    }
    s = wsum(s); q = wsum(q);
    if (lane == 0){ atomicAdd(&sacc[w], s); atomicAdd(&qacc[w], q); }
  }
  __syncthreads();
  if (tid < 4){
    atomicAdd(&g_st[384 + (cb + tid) * 2], (double)sacc[tid]);
    atomicAdd(&g_st[384 + (cb + tid) * 2 + 1], (double)qacc[tid]);
  }
}

// ---------------- bn_d1 factors + raw dw2 transpose ----------------
__global__ void k_foldd2(const float* __restrict__ dg1, const float* __restrict__ dbe1,
                         const float* __restrict__ dw2, const float* __restrict__ db2){
  int tid = threadIdx.x;
  if (blockIdx.x == 0 && tid < 64){
    double m = g_st[384 + tid * 2] / 191912.0, v = g_st[384 + tid * 2 + 1] / 191912.0 - m * m;
    float sc = dg1[tid] / sqrtf((float)v + 1e-5f);
    g_sd1[tid] = sc; g_shd1[tid] = dbe1[tid] - (float)m * sc;
    g_db2f[tid] = db2[tid];
  }
  int gt = blockIdx.x * 256 + tid;
  for (int i = gt; i < 64 * 5 * 64; i += 32 * 256){
    int co = i & 63, r = i >> 6, k = r % 5, ci = r / 5;
    g_dw2f[i] = dw2[(co * 64 + ci) * 5 + k];
  }
}

// ---------------- dconv2: t-tile 384, 16co/wave x 6t/lane, global weights (amortize weight stream) ----------------
__global__ void __launch_bounds__(256) k_dconv2(){
  __shared__ float xs[32][388];            // 48.5 KB
  __shared__ float sdl[64], shdl[64];
  __shared__ float sacc[64], qacc[64];
  int tid = threadIdx.x, b = blockIdx.y, t0 = blockIdx.x * 384;
  int lane = tid & 63, wv = tid >> 6;
  int cb = wv * 16;
  if (tid < 64){ sdl[tid] = g_sd1[tid]; shdl[tid] = g_shd1[tid]; sacc[tid] = 0.f; qacc[tid] = 0.f; }
  float acc[6][16];
  #pragma unroll
  for (int j = 0; j < 6; j++)
    #pragma unroll
    for (int i = 0; i < 16; i++) acc[j][i] = g_db2f[cb + i];
  for (int half = 0; half < 2; ++half){
    __syncthreads();
    for (int i = tid; i < 32 * 388; i += 256){
      int ci = i / 388, tt = i - ci * 388, g = t0 - 2 + tt;
      int cia = half * 32 + ci;
      xs[ci][tt] = ((unsigned)g < TD) ? (sdl[cia] * g_yd1[(b * 64 + cia) * TD + g] + shdl[cia]) : 0.f;
    }
    __syncthreads();
    for (int ci = 0; ci < 32; ci++){
      int cia = half * 32 + ci;
      #pragma unroll
      for (int k = 0; k < 5; k++){
        const float4* wp = (const float4*)(g_dw2f + (cia * 5 + k) * 64 + cb);
        float4 w0 = wp[0], w1 = wp[1], w2v = wp[2], w3v = wp[3];
        float wr[16] = { w0.x, w0.y, w0.z, w0.w, w1.x, w1.y, w1.z, w1.w,
                         w2v.x, w2v.y, w2v.z, w2v.w, w3v.x, w3v.y, w3v.z, w3v.w };
        #pragma unroll
        for (int j = 0; j < 6; j++){
          float xv = xs[ci][lane + 64 * j + k];
          #pragma unroll
          for (int i = 0; i < 16; i++) acc[j][i] += wr[i] * xv;
        }
      }
    }
  }
  #pragma unroll
  for (int i = 0; i < 16; i++){
    int co = cb + i;
    float s = 0.f, q = 0.f;
    #pragma unroll
    for (int j = 0; j < 6; j++){
      int t = t0 + lane + 64 * j;
      bool ok = t < TD;
      float a = acc[j][i];
      float o = ok ? a / (1.f + expf(-a)) : 0.f;
      if (ok) g_yd2[(b * 64 + co) * TD + t] = o;
      s += o; q += o * o;
    }
    s = wsum(s); q = wsum(q);
    if (lane == 0){ atomicAdd(&sacc[co], s); atomicAdd(&qacc[co], q); }
  }
  __syncthreads();
  if (tid < 64){
    atomicAdd(&g_st[512 + tid * 2], (double)sacc[tid]);
    atomicAdd(&g_st[512 + tid * 2 + 1], (double)qacc[tid]);
  }
}

// ---------------- recon ----------------
__global__ void k_recon(const float* __restrict__ dg2, const float* __restrict__ dbe2,
                        const float* __restrict__ dw3, const float* __restrict__ db3,
                        float* __restrict__ outR){
  __shared__ float wf[64];
  __shared__ float bsh2;
  int tid = threadIdx.x, b = blockIdx.y, t0 = blockIdx.x * 256;
  if (tid < 64){
    double m = g_st[512 + tid * 2] / 191912.0, v = g_st[512 + tid * 2 + 1] / 191912.0 - m * m;
    float sc = dg2[tid] / sqrtf((float)v + 1e-5f);
    float shv = dbe2[tid] - (float)m * sc;
    wf[tid] = dw3[tid] * sc;
    float contrib = wsum(dw3[tid] * shv);
    if (tid == 0) bsh2 = db3[0] + contrib;
  }
  __syncthreads();
  int t = t0 + tid;
  if (t < TT){
    if (t < TD){
      float a = bsh2;
      for (int ci = 0; ci < 64; ci++) a += wf[ci] * g_yd2[(b * 64 + ci) * TD + t];
      outR[b * TT + t] = a;
    } else {
      outR[b * TT + t] = 0.f;
    }
  }
}

// ---------------- launch ----------------
extern "C" void kernel_launch(void* const* d_in, const int* in_sizes, int n_in,
                              void* d_out, int out_size, void* d_ws, size_t ws_size,
                              hipStream_t stream){
  (void)in_sizes; (void)n_in; (void)out_size; (void)d_ws; (void)ws_size;
  const float* x    = (const float*)d_in[0];
  const float* w1   = (const float*)d_in[1];
  const float* b1   = (const float*)d_in[2];
  const float* g1   = (const float*)d_in[3];
  const float* be1  = (const float*)d_in[4];
  const float* w2   = (const float*)d_in[5];
  const float* b2   = (const float*)d_in[6];
  const float* g2   = (const float*)d_in[7];
  const float* be2  = (const float*)d_in[8];
  const float* w3   = (const float*)d_in[9];
  const float* b3   = (const float*)d_in[10];
  const float* g3   = (const float*)d_in[11];
  const float* be3  = (const float*)d_in[12];
  const float* embed= (const float*)d_in[13];
  const float* dw1  = (const float*)d_in[14];
  const float* dg1  = (const float*)d_in[15];
  const float* dbe1 = (const float*)d_in[16];
  const float* dw2  = (const float*)d_in[17];
  const float* db2  = (const float*)d_in[18];
  const float* dg2  = (const float*)d_in[19];
  const float* dbe2 = (const float*)d_in[20];
  const float* dw3  = (const float*)d_in[21];
  const float* db3  = (const float*)d_in[22];
  const int* oidx   = (const int*)d_in[23];

  float* out    = (float*)d_out;
  float* outIdx = out + 192000;
  float* outS   = out + 208000;

  hipLaunchKernelGGL(k_zero, dim3(32), dim3(256), 0, stream);
  hipLaunchKernelGGL(k_embprep, dim3(64), dim3(256), 0, stream, embed);
  hipLaunchKernelGGL(k_conv1, dim3(94, 8), dim3(256), 0, stream, x, w1, b1);
  hipLaunchKernelGGL(k_fold2, dim3(8), dim3(256), 0, stream, g1, be1, w2, b2);
  hipLaunchKernelGGL(k_conv2, dim3(94, 8), dim3(256), 0, stream);
  hipLaunchKernelGGL(k_fold3, dim3(64), dim3(256), 0, stream, g2, be2, w3, b3);
  hipLaunchKernelGGL(k_conv3, dim3(63, 8), dim3(256), 0, stream);
  hipLaunchKernelGGL(k_stats, dim3(8, 64), dim3(256), 0, stream, 0, NZ, 256);
  hipLaunchKernelGGL(k_zbn, dim3(32, 8), dim3(256), 0, stream, g3, be3);
  hipLaunchKernelGGL(k_zsplit, dim3(4000), dim3(256), 0, stream);
  hipLaunchKernelGGL(k_vq1, dim3(250, 8), dim3(256), 0, stream);
  hipLaunchKernelGGL(k_vq1b, dim3(63), dim3(256), 0, stream);
  hipLaunchKernelGGL(k_vq3, dim3(4000), dim3(256), 0, stream, embed, outIdx);
  hipLaunchKernelGGL(k_orthoprep, dim3(1), dim3(256), 0, stream, embed, oidx);
  hipLaunchKernelGGL(k_ortho, dim3(64), dim3(256), 0, stream);
  hipLaunchKernelGGL(k_div, dim3(1), dim3(256), 0, stream, outS);
  hipLaunchKernelGGL(k_zq, dim3(32, 8), dim3(256), 0, stream, embed);
  hipLaunchKernelGGL(k_folddw1, dim3(100), dim3(256), 0, stream, dw1);
  hipLaunchKernelGGL(k_dconv1, dim3(32, 8, 16), dim3(256), 0, stream);
  hipLaunchKernelGGL(k_foldd2, dim3(32), dim3(256), 0, stream, dg1, dbe1, dw2, db2);
  hipLaunchKernelGGL(k_dconv2, dim3(63, 8), dim3(256), 0, stream);
  hipLaunchKernelGGL(k_recon, dim3(94, 8), dim3(256), 0, stream, dg2, dbe2, dw3, db3, out);
}

// Round 29
// 892.885 us; speedup vs baseline: 1.2475x; 1.2475x over previous
//
#include <hip/hip_runtime.h>
#include <math.h>
#include <float.h>

#define DEV __device__ __forceinline__

#define BB 8
#define TT 24000
#define TD 23989
#define NZ 2000
#define ROWS 16000
#define NE 8192
#define NCG 8

typedef __attribute__((ext_vector_type(8))) short bf16x8;
typedef __attribute__((ext_vector_type(4))) float f32x4;

// ---------------- static device storage ----------------
__device__ double g_st[640];
__device__ double g_misc[2];
__device__ float  g_e2[NE];
__device__ float  g_avg[NE];
__device__ float  g_z2[ROWS];
__device__ float  g_rdm[ROWS];
__device__ int    g_rix[ROWS];
__device__ float  g_ob[256 * 64];
__device__ float  g_pmd[ROWS * NCG];
__device__ int    g_pmi[ROWS * NCG];
__device__ int    g_pcc[ROWS * NCG];
__device__ float2 g_cand[ROWS * 256];
__device__ unsigned short g_zbh[ROWS * 64], g_zbl[ROWS * 64];
__device__ unsigned short g_ebh[NE * 64],  g_ebl[NE * 64];
__device__ float  g_s1[16], g_sh1[16];
__device__ float  g_s2[32], g_sh2[32];
__device__ float  g_sd1[64], g_shd1[64];
__device__ float  g_w2f[2560];
__device__ float  g_b2f[32];
__device__ float  g_w3f[64 * 32 * 25];
__device__ float  g_b3f[64];
__device__ float  g_dw2f[64 * 5 * 64];
__device__ float  g_db2f[64];
__device__ float  g_dw1t[64 * 64 * 25];
__device__ float  g_zbn[ROWS * 64];
__device__ double g_zbnd[ROWS * 64];
__device__ float  g_zq[BB * 64 * NZ];
__device__ float  g_y1[BB * 16 * TT];
__device__ float  g_zpre[BB * 64 * NZ];
__device__ float  g_yd1[BB * 64 * TD];
__device__ float  g_y2[BB * 32 * TT];
__device__ float  g_yd2[BB * 64 * TD];

DEV float wsum(float v){
  #pragma unroll
  for (int o = 32; o; o >>= 1) v += __shfl_xor(v, o, 64);
  return v;
}
DEV int clampc(int c){ return c < 0 ? 0 : (c > NE - 1 ? NE - 1 : c); }
DEV float bss(unsigned short s){ union { unsigned u; float f; } v; v.u = ((unsigned)s) << 16; return v.f; }
DEV unsigned short f2bs(float f){
  union { float f; unsigned u; } v; v.f = f;
  unsigned r = (v.u + 0x7FFF + ((v.u >> 16) & 1)) >> 16;
  return (unsigned short)r;
}

__global__ void k_zero(){
  int i = blockIdx.x * 256 + threadIdx.x;
  if (i < 640) g_st[i] = 0.0;
  if (i < 2) g_misc[i] = 0.0;
  if (i < NE) g_avg[i] = 0.f;
}

// ---------------- embed prep: |e|^2 + bf16 split ----------------
__global__ void k_embprep(const float* __restrict__ embed){
  int gt = blockIdx.x * 256 + threadIdx.x;
  int gs = gridDim.x * 256;
  for (int i = gt; i < NE * 64; i += gs){
    float v = embed[i];
    unsigned short h = f2bs(v);
    g_ebh[i] = h;
    g_ebl[i] = f2bs(v - bss(h));
  }
  for (int c = gt; c < NE; c += gs){
    float s = 0.f;
    for (int j = 0; j < 64; j++){ float v = embed[c * 64 + j]; s += v * v; }
    g_e2[c] = s;
  }
}

// ---------------- z bf16 split (after zbn) ----------------
__global__ void k_zsplit(){
  int i = blockIdx.x * 256 + threadIdx.x;
  if (i < ROWS * 64){
    float v = g_zbn[i];
    unsigned short h = f2bs(v);
    g_zbh[i] = h;
    g_zbl[i] = f2bs(v - bss(h));
  }
}

// ---------------- conv1: silu + stats ----------------
__global__ void k_conv1(const float* __restrict__ x, const float* __restrict__ w1,
                        const float* __restrict__ b1){
  int b = blockIdx.y, t0 = blockIdx.x * 256, tid = threadIdx.x;
  __shared__ float xs[260], wl[80], bl[16], sacc[16], qacc[16];
  if (tid < 80) wl[tid] = w1[tid];
  if (tid < 16){ bl[tid] = b1[tid]; sacc[tid] = 0.f; qacc[tid] = 0.f; }
  for (int i = tid; i < 260; i += 256){ int g = t0 - 2 + i; xs[i] = ((unsigned)g < TT) ? x[b * TT + g] : 0.f; }
  __syncthreads();
  int t = t0 + tid;
  bool ok = t < TT;
  float xv[5];
  #pragma unroll
  for (int k = 0; k < 5; k++) xv[k] = xs[tid + k];
  float out[16];
  #pragma unroll
  for (int c = 0; c < 16; c++){
    float a = bl[c];
    #pragma unroll
    for (int k = 0; k < 5; k++) a += wl[c * 5 + k] * xv[k];
    float o = ok ? a / (1.f + expf(-a)) : 0.f;
    out[c] = o;
    if (ok) g_y1[(b * 16 + c) * TT + t] = o;
  }
  int lane = tid & 63;
  #pragma unroll
  for (int c = 0; c < 16; c++){
    float s = wsum(out[c]);
    float q = wsum(out[c] * out[c]);
    if (lane == 0){ atomicAdd(&sacc[c], s); atomicAdd(&qacc[c], q); }
  }
  __syncthreads();
  if (tid < 16){ atomicAdd(&g_st[tid * 2], (double)sacc[tid]); atomicAdd(&g_st[tid * 2 + 1], (double)qacc[tid]); }
}

// ---------------- bn1 factors + raw w2 transpose ----------------
__global__ void k_fold2(const float* __restrict__ g1, const float* __restrict__ be1,
                        const float* __restrict__ w2, const float* __restrict__ b2){
  int tid = threadIdx.x;
  if (blockIdx.x == 0 && tid < 16){
    double m = g_st[tid * 2] / 192000.0, v = g_st[tid * 2 + 1] / 192000.0 - m * m;
    float s = g1[tid] / sqrtf((float)v + 1e-5f);
    g_s1[tid] = s; g_sh1[tid] = be1[tid] - (float)m * s;
  }
  if (blockIdx.x == 0 && tid < 32) g_b2f[tid] = b2[tid];
  int gt = blockIdx.x * 256 + tid;
  for (int i = gt; i < 2560; i += 8 * 256){
    int co = i & 31, r = i >> 5, k = r % 5, ci = r / 5;
    g_w2f[i] = w2[(co * 16 + ci) * 5 + k];
  }
}

// ---------------- conv2: 8co/wave x 4t/lane, BN at stage-in, silu, stats ----------------
__global__ void __launch_bounds__(256) k_conv2(){
  int b = blockIdx.y, t0 = blockIdx.x * 256, tid = threadIdx.x;
  __shared__ float xs[16][260];
  __shared__ float sacc[32], qacc[32];
  __shared__ float s1l[16], sh1l[16];
  int lane = tid & 63, wv = tid >> 6;
  int cb = wv * 8;
  if (tid < 32){ sacc[tid] = 0.f; qacc[tid] = 0.f; }
  if (tid < 16){ s1l[tid] = g_s1[tid]; sh1l[tid] = g_sh1[tid]; }
  __syncthreads();
  for (int i = tid; i < 16 * 260; i += 256){
    int ci = i / 260, tt = i - ci * 260, g = t0 - 2 + tt;
    xs[ci][tt] = ((unsigned)g < TT) ? (s1l[ci] * g_y1[(b * 16 + ci) * TT + g] + sh1l[ci]) : 0.f;
  }
  __syncthreads();
  float acc[4][8];
  #pragma unroll
  for (int j = 0; j < 4; j++)
    #pragma unroll
    for (int i = 0; i < 8; i++) acc[j][i] = g_b2f[cb + i];
  for (int ci = 0; ci < 16; ci++){
    #pragma unroll
    for (int k = 0; k < 5; k++){
      const float4* wp = (const float4*)(g_w2f + (ci * 5 + k) * 32 + cb);
      float4 w0 = wp[0], w1v = wp[1];
      float wr[8] = { w0.x, w0.y, w0.z, w0.w, w1v.x, w1v.y, w1v.z, w1v.w };
      #pragma unroll
      for (int j = 0; j < 4; j++){
        float xv = xs[ci][lane + 64 * j + k];
        #pragma unroll
        for (int i = 0; i < 8; i++) acc[j][i] += wr[i] * xv;
      }
    }
  }
  #pragma unroll
  for (int i = 0; i < 8; i++){
    int co = cb + i;
    float s = 0.f, q = 0.f;
    #pragma unroll
    for (int j = 0; j < 4; j++){
      int t = t0 + lane + 64 * j;
      bool ok = t < TT;
      float a = acc[j][i];
      float o = ok ? a / (1.f + expf(-a)) : 0.f;
      if (ok) g_y2[(b * 32 + co) * TT + t] = o;
      s += o; q += o * o;
    }
    s = wsum(s); q = wsum(q);
    if (lane == 0){ atomicAdd(&sacc[co], s); atomicAdd(&qacc[co], q); }
  }
  __syncthreads();
  if (tid < 32){ atomicAdd(&g_st[128 + tid * 2], (double)sacc[tid]); atomicAdd(&g_st[128 + tid * 2 + 1], (double)qacc[tid]); }
}

// ---------------- bn2 factors + raw w3 transpose ----------------
__global__ void k_fold3(const float* __restrict__ g2, const float* __restrict__ be2,
                        const float* __restrict__ w3, const float* __restrict__ b3){
  int tid = threadIdx.x;
  if (blockIdx.x == 0 && tid < 32){
    double m = g_st[128 + tid * 2] / 192000.0, v = g_st[128 + tid * 2 + 1] / 192000.0 - m * m;
    float s = g2[tid] / sqrtf((float)v + 1e-5f);
    g_s2[tid] = s; g_sh2[tid] = be2[tid] - (float)m * s;
  }
  if (blockIdx.x == 0 && tid >= 64 && tid < 128) g_b3f[tid - 64] = b3[tid - 64];
  int gt = blockIdx.x * 256 + tid;
  for (int i = gt; i < 64 * 32 * 25; i += 64 * 256){
    int co = i & 63, r = i >> 6, k = r % 25, ci = r / 25;
    g_w3f[i] = w3[(co * 32 + ci) * 25 + k];
  }
}

// ---------------- conv3: 16co/wave, lane=(t32,ci-half), shfl reduce, tanh ----------------
__global__ void __launch_bounds__(256) k_conv3(){
  __shared__ float xs[32][400];
  __shared__ float s2l[32], sh2l[32];
  int tid = threadIdx.x, b = blockIdx.y, t0 = blockIdx.x * 32;
  int lane = tid & 63, wv = tid >> 6;
  int cb = wv * 16;
  int tl = lane & 31, h = lane >> 5;
  if (tid < 32){ s2l[tid] = g_s2[tid]; sh2l[tid] = g_sh2[tid]; }
  __syncthreads();
  int p0 = t0 * 12 - 12;
  for (int i = tid; i < 32 * 397; i += 256){
    int ci = i / 397, pp = i - ci * 397, g = p0 + pp;
    xs[ci][pp] = ((unsigned)g < TT) ? (s2l[ci] * g_y2[(b * 32 + ci) * TT + g] + sh2l[ci]) : 0.f;
  }
  __syncthreads();
  float acc[16];
  #pragma unroll
  for (int i = 0; i < 16; i++) acc[i] = 0.f;
  for (int cii = 0; cii < 16; cii++){
    int ci = h * 16 + cii;
    #pragma unroll
    for (int k = 0; k < 25; k++){
      float xv = xs[ci][tl * 12 + k];
      const float4* wp = (const float4*)(g_w3f + (ci * 25 + k) * 64 + cb);
      float4 a0 = wp[0], a1 = wp[1], a2 = wp[2], a3 = wp[3];
      acc[0] += a0.x * xv; acc[1] += a0.y * xv; acc[2] += a0.z * xv; acc[3] += a0.w * xv;
      acc[4] += a1.x * xv; acc[5] += a1.y * xv; acc[6] += a1.z * xv; acc[7] += a1.w * xv;
      acc[8] += a2.x * xv; acc[9] += a2.y * xv; acc[10] += a2.z * xv; acc[11] += a2.w * xv;
      acc[12] += a3.x * xv; acc[13] += a3.y * xv; acc[14] += a3.z * xv; acc[15] += a3.w * xv;
    }
  }
  #pragma unroll
  for (int i = 0; i < 16; i++) acc[i] += __shfl_xor(acc[i], 32, 64);
  int t = t0 + tl;
  if (h == 0 && t < NZ){
    #pragma unroll
    for (int i = 0; i < 16; i++)
      g_zpre[(b * 64 + cb + i) * NZ + t] = tanhf(acc[i] + g_b3f[cb + i]);
  }
}

// ---------------- per-channel stats (zpre only) ----------------
__global__ void k_stats(int which, int L, int stoff){
  const float* p = (which == 0) ? g_zpre : (which == 1) ? g_yd1 : g_yd2;
  int co = blockIdx.y, t0 = blockIdx.x * 256, tid = threadIdx.x;
  int t = t0 + tid;
  float s = 0.f, q = 0.f;
  if (t < L){
    for (int b = 0; b < BB; b++){ float v = p[(b * 64 + co) * L + t]; s += v; q += v * v; }
  }
  s = wsum(s); q = wsum(q);
  __shared__ float sa[4], qa[4];
  int w = tid >> 6, lane = tid & 63;
  if (lane == 0){ sa[w] = s; qa[w] = q; }
  __syncthreads();
  if (tid == 0){
    atomicAdd(&g_st[stoff + co * 2], (double)(sa[0] + sa[1] + sa[2] + sa[3]));
    atomicAdd(&g_st[stoff + co * 2 + 1], (double)(qa[0] + qa[1] + qa[2] + qa[3]));
  }
}

// ---------------- bn3 apply + transpose rows + |z|^2 (+f64 copy) ----------------
__global__ void k_zbn(const float* __restrict__ g3, const float* __restrict__ be3){
  __shared__ float tile[64][65];
  __shared__ float s3[64], sh3[64];
  __shared__ double s3d[64], sh3d[64];
  int tid = threadIdx.x, b = blockIdx.y, n0 = blockIdx.x * 64;
  if (tid < 64){
    double m = g_st[256 + tid * 2] / 16000.0, v = g_st[256 + tid * 2 + 1] / 16000.0 - m * m;
    double sd = (double)g3[tid] / sqrt(v + 1e-5);
    double shd = (double)be3[tid] - m * sd;
    s3d[tid] = sd; sh3d[tid] = shd;
    s3[tid] = (float)sd; sh3[tid] = (float)shd;
  }
  __syncthreads();
  for (int i = tid; i < 64 * 64; i += 256){
    int c = i >> 6, nn = i & 63, n = n0 + nn;
    tile[c][nn] = (n < NZ) ? (s3[c] * g_zpre[(b * 64 + c) * NZ + n] + sh3[c]) : 0.f;
  }
  __syncthreads();
  int lane = tid & 63;
  for (int it = 0; it < 16; ++it){
    int nn = (tid >> 6) + it * 4;
    int n = n0 + nn, c = lane;
    if (n < NZ){
      float v = tile[c][nn];
      int row = b * NZ + n;
      g_zbn[row * 64 + c] = v;
      g_zbnd[row * 64 + c] = s3d[c] * (double)g_zpre[(b * 64 + c) * NZ + n] + sh3d[c];
      float s = wsum(v * v);
      if (lane == 0) g_z2[row] = s;
    }
  }
}

// ---------------- VQ pass 1: split-bf16 MFMA distance scan (per-chunk thr reduce) ----------------
__global__ void __launch_bounds__(256) k_vq1(){
  __shared__ unsigned short bsh[64 * 72];
  __shared__ unsigned short bsl[64 * 72];
  __shared__ float2 ring[64][16];
  __shared__ int cnt[64];
  int tid = threadIdx.x, lane = tid & 63, w = tid >> 6;
  int q = lane >> 4, col = lane & 15;
  int rowbase = blockIdx.x * 64 + w * 16;
  int cbase = blockIdx.y * 1024;
  int grp = blockIdx.y;
  if (tid < 64) cnt[tid] = 0;
  #pragma unroll
  for (int i = 0; i < 4; i++)
    ring[w * 16 + (lane & 15)][(lane >> 4) * 4 + i] = make_float2(FLT_MAX, __int_as_float(NE - 1));
  bf16x8 ah0, ah1, al0, al1;
  {
    const unsigned short* zh = g_zbh + (rowbase + col) * 64;
    const unsigned short* zl = g_zbl + (rowbase + col) * 64;
    ah0 = *(const bf16x8*)(zh + q * 8);
    ah1 = *(const bf16x8*)(zh + 32 + q * 8);
    al0 = *(const bf16x8*)(zl + q * 8);
    al1 = *(const bf16x8*)(zl + 32 + q * 8);
  }
  float z2r[4];
  #pragma unroll
  for (int r = 0; r < 4; r++) z2r[r] = g_z2[rowbase + q * 4 + r];
  float thr[4], lmin[4]; int lamc[4];
  #pragma unroll
  for (int r = 0; r < 4; r++){ thr[r] = FLT_MAX; lmin[r] = FLT_MAX; lamc[r] = NE - 1; }
  float runmin[4] = {FLT_MAX, FLT_MAX, FLT_MAX, FLT_MAX};
  for (int ch = 0; ch < 16; ++ch){
    __syncthreads();
    {
      int cl = tid >> 2, seg = tid & 3;
      int cglob = cbase + ch * 64 + cl;
      *(int4*)&bsh[cl * 72 + seg * 16]     = *(const int4*)(g_ebh + cglob * 64 + seg * 16);
      *(int4*)&bsh[cl * 72 + seg * 16 + 8] = *(const int4*)(g_ebh + cglob * 64 + seg * 16 + 8);
      *(int4*)&bsl[cl * 72 + seg * 16]     = *(const int4*)(g_ebl + cglob * 64 + seg * 16);
      *(int4*)&bsl[cl * 72 + seg * 16 + 8] = *(const int4*)(g_ebl + cglob * 64 + seg * 16 + 8);
    }
    __syncthreads();
    float d2s[4][4];
    float tmin[4] = {FLT_MAX, FLT_MAX, FLT_MAX, FLT_MAX};
    #pragma unroll
    for (int t = 0; t < 4; t++){
      int ct = cbase + ch * 64 + t * 16;
      const unsigned short* bhp = &bsh[(t * 16 + col) * 72];
      const unsigned short* blp = &bsl[(t * 16 + col) * 72];
      bf16x8 bh0 = *(const bf16x8*)(bhp + q * 8);
      bf16x8 bh1 = *(const bf16x8*)(bhp + 32 + q * 8);
      bf16x8 bl0 = *(const bf16x8*)(blp + q * 8);
      bf16x8 bl1 = *(const bf16x8*)(blp + 32 + q * 8);
      f32x4 acc = {0.f, 0.f, 0.f, 0.f};
      acc = __builtin_amdgcn_mfma_f32_16x16x32_bf16(al0, bh0, acc, 0, 0, 0);
      acc = __builtin_amdgcn_mfma_f32_16x16x32_bf16(al1, bh1, acc, 0, 0, 0);
      acc = __builtin_amdgcn_mfma_f32_16x16x32_bf16(ah0, bl0, acc, 0, 0, 0);
      acc = __builtin_amdgcn_mfma_f32_16x16x32_bf16(ah1, bl1, acc, 0, 0, 0);
      acc = __builtin_amdgcn_mfma_f32_16x16x32_bf16(ah0, bh0, acc, 0, 0, 0);
      acc = __builtin_amdgcn_mfma_f32_16x16x32_bf16(ah1, bh1, acc, 0, 0, 0);
      float e2c = g_e2[ct + col];
      #pragma unroll
      for (int r = 0; r < 4; r++){
        float d = z2r[r] + e2c - 2.f * acc[r];
        d2s[t][r] = d;
        if (d < lmin[r]){ lmin[r] = d; lamc[r] = ct + col; }
        tmin[r] = fminf(tmin[r], d);
      }
    }
    #pragma unroll
    for (int r = 0; r < 4; r++){
      float m = tmin[r];
      m = fminf(m, __shfl_xor(m, 1, 64));
      m = fminf(m, __shfl_xor(m, 2, 64));
      m = fminf(m, __shfl_xor(m, 4, 64));
      m = fminf(m, __shfl_xor(m, 8, 64));
      if (m < runmin[r]){
        runmin[r] = m;
        thr[r] = m + 0.71f * sqrtf(fmaxf(m, 0.f)) + 0.13f;
      }
    }
    #pragma unroll
    for (int t = 0; t < 4; t++){
      int ct = cbase + ch * 64 + t * 16;
      bool any = false;
      #pragma unroll
      for (int r = 0; r < 4; r++) if (d2s[t][r] < thr[r]) any = true;
      if (__ballot(any)){
        #pragma unroll
        for (int r = 0; r < 4; r++){
          if (d2s[t][r] < thr[r]){
            int lr = w * 16 + q * 4 + r;
            int s = atomicAdd(&cnt[lr], 1) & 15;
            ring[lr][s] = make_float2(sqrtf(fmaxf(d2s[t][r], 1e-12f)), __int_as_float(ct + col));
          }
        }
      }
    }
  }
  __syncthreads();
  #pragma unroll
  for (int r = 0; r < 4; r++){
    float m = lmin[r]; int c = lamc[r];
    #pragma unroll
    for (int o = 1; o <= 8; o <<= 1){
      float om = __shfl_xor(m, o, 64);
      int oc = __shfl_xor(c, o, 64);
      if (om < m || (om == m && oc < c)){ m = om; c = oc; }
    }
    if (col == 0){
      int gr = rowbase + q * 4 + r;
      g_pmd[gr * NCG + grp] = m;
      g_pmi[gr * NCG + grp] = c;
    }
  }
  if (lane < 16){
    int lr = w * 16 + lane;
    g_pcc[(rowbase + lane) * NCG + grp] = cnt[lr];
  }
  #pragma unroll
  for (int i = 0; i < 4; i++){
    int idx = lane * 4 + i;
    int lr = idx >> 4, s = idx & 15;
    g_cand[(rowbase + lr) * 256 + grp * 16 + s] = ring[w * 16 + lr][s];
  }
}

__global__ void k_vq1b(){
  int row = blockIdx.x * 256 + threadIdx.x;
  if (row >= ROWS) return;
  float best = FLT_MAX; int bi = NE - 1;
  for (int cg = 0; cg < NCG; ++cg){
    float d = g_pmd[row * NCG + cg]; int i = g_pmi[row * NCG + cg];
    if (d < best || (d == best && i < bi)){ best = d; bi = i; }
  }
  g_rdm[row] = sqrtf(fmaxf(best, 1e-12f));
  g_rix[row] = bi;
}

// ---------------- VQ pass 3: wave-cooperative f64 re-rank + block-level commit atomic ----------------
// grid.x * 4 == ROWS exactly (4000 * 4 = 16000): no early-return divergence.
__global__ void __launch_bounds__(256) k_vq3(const float* __restrict__ embed,
                                             float* __restrict__ outIdx){
  __shared__ int   ccode[4][144];
  __shared__ float cdst[4][144];
  __shared__ int   cn[4];
  __shared__ double bsum[4];
  int w = threadIdx.x >> 6, lane = threadIdx.x & 63;
  int row = blockIdx.x * 4 + w;
  float dmin = g_rdm[row];
  int seedc = clampc(g_rix[row]);
  if (lane == 0){ cn[w] = 0; ccode[w][0] = seedc; }
  __syncthreads();
  if (lane == 0) cn[w] = 1;
  int grp = lane & 7;
  int sub = lane >> 3;
  int cnt = g_pcc[row * NCG + grp]; if (cnt > 16) cnt = 16;
  int s0 = sub * 2, s1 = s0 + 2; if (s1 > cnt) s1 = cnt;
  for (int s = s0; s < s1; ++s){
    float2 cd = g_cand[row * 256 + grp * 16 + s];
    float dist = cd.x; int c = clampc(__float_as_int(cd.y));
    if (dist <= dmin + 0.353f && c != seedc){
      int i = atomicAdd(&cn[w], 1);
      ccode[w][i] = c;
    }
  }
  __syncthreads();
  int n = cn[w];
  double zdl = g_zbnd[row * 64 + lane];
  double bd = DBL_MAX; int bc = NE - 1;
  for (int i = 0; i < n; i++){
    int c = ccode[w][i];
    double diff = zdl - (double)embed[c * 64 + lane];
    double d = diff * diff;
    #pragma unroll
    for (int o = 32; o; o >>= 1) d += __shfl_xor(d, o, 64);
    if (lane == 0) cdst[w][i] = (float)d;
    if (d < bd || (d == bd && c < bc)){ bd = d; bc = c; }
  }
  __syncthreads();
  float dminE = (float)sqrt(bd);
  float Zp = 0.f;
  for (int i = lane; i < n; i += 64)
    Zp += expf(-100.f * (sqrtf(cdst[w][i]) - dminE));
  float Z = fmaxf(wsum(Zp), 1e-30f);
  if (lane == 0){
    g_rix[row] = bc;
    outIdx[row] = (float)bc;
    bsum[w] = bd;
  }
  for (int i = lane; i < n; i += 64)
    atomicAdd(&g_avg[ccode[w][i]], expf(-100.f * (sqrtf(cdst[w][i]) - dminE)) / Z);
  __syncthreads();
  if (threadIdx.x == 0)
    atomicAdd(&g_misc[0], bsum[0] + bsum[1] + bsum[2] + bsum[3]);
}

__global__ void k_orthoprep(const float* __restrict__ embed, const int* __restrict__ oidx){
  int tid = threadIdx.x;
  int c = clampc(oidx[tid]);
  float s = 0.f;
  for (int j = 0; j < 64; j++){ float v = embed[c * 64 + j]; s += v * v; }
  float r = 1.f / sqrtf(s + 1e-12f);
  for (int j = 0; j < 64; j++) g_ob[tid * 64 + j] = embed[c * 64 + j] * r;
}

__global__ void k_ortho(){
  int w = threadIdx.x >> 6, lane = threadIdx.x & 63;
  int i = blockIdx.x * 4 + w;
  float acc = 0.f;
  for (int j = lane; j < 256; j += 64){
    float d = 0.f;
    for (int k = 0; k < 64; k++) d += g_ob[i * 64 + k] * g_ob[j * 64 + k];
    acc += d * d;
  }
  acc = wsum(acc);
  if (lane == 0) atomicAdd(&g_misc[1], (double)acc);
}

__global__ void k_div(float* __restrict__ outS){
  int tid = threadIdx.x;
  double part = 0.0;
  for (int c = tid; c < NE; c += 256){
    double p = (double)g_avg[c] / 16000.0;
    double pc = p < 1e-30 ? 1e-30 : p;
    part += p * log(pc);
  }
  __shared__ double red[256];
  red[tid] = part; __syncthreads();
  for (int o = 128; o; o >>= 1){ if (tid < o) red[tid] += red[tid + o]; __syncthreads(); }
  if (tid == 0){
    double diversity = red[0];
    double commit = g_misc[0] / (double)(ROWS * 64);
    double ortho = g_misc[1] / 65536.0 - 1.0 / 256.0;
    double loss = commit + diversity + ortho;
    outS[0] = (float)loss;
    outS[1] = (float)commit;
    outS[2] = (float)diversity;
    outS[3] = (float)ortho;
  }
}

__global__ void k_zq(const float* __restrict__ embed){
  __shared__ float tile[64][65];
  int tid = threadIdx.x, b = blockIdx.y, n0 = blockIdx.x * 64;
  for (int i = tid; i < 64 * 64; i += 256){
    int nn = i >> 6, c = i & 63;
    int n = n0 + nn;
    int code = (n < NZ) ? clampc(g_rix[b * NZ + n]) : 0;
    tile[c][nn] = embed[code * 64 + c];
  }
  __syncthreads();
  for (int i = tid; i < 64 * 64; i += 256){
    int c = i >> 6, nn = i & 63;
    int n = n0 + nn;
    if (n < NZ) g_zq[(b * 64 + c) * NZ + n] = tile[c][nn];
  }
}

__global__ void k_folddw1(const float* __restrict__ dw1){
  int gt = blockIdx.x * 256 + threadIdx.x;
  for (int i = gt; i < 64 * 64 * 25; i += 100 * 256){
    int co = i & 63, r = i >> 6, k = r % 25, ci = r / 25;
    g_dw1t[i] = dw1[(ci * 64 + co) * 25 + (24 - k)];
  }
}

// ---------------- dconv1: LDS weight staging (4 ch/block, 1 ch/wave), static acc ----------------
__global__ void __launch_bounds__(256) k_dconv1(){
  __shared__ float xsd[64][68];
  __shared__ float wsh[64 * 25 * 4];
  __shared__ float sacc[4], qacc[4];
  int tid = threadIdx.x, b = blockIdx.y;
  int cb = blockIdx.z * 4;
  int t0 = blockIdx.x * 768;
  int nb = t0 / 12 - 1;
  if (tid < 4){ sacc[tid] = 0.f; qacc[tid] = 0.f; }
  for (int i = tid; i < 64 * 67; i += 256){
    int ci = i / 67, nl = i - ci * 67, n = nb + nl;
    xsd[ci][nl] = ((unsigned)n < NZ) ? g_zq[(b * 64 + ci) * NZ + n] : 0.f;
  }
  for (int i = tid; i < 64 * 25 * 4; i += 256){
    int r = i >> 2, c = i & 3;
    wsh[i] = g_dw1t[r * 64 + cb + c];
  }
  __syncthreads();
  int w = tid >> 6, lane = tid & 63;
  float acc[12];
  #pragma unroll
  for (int p = 0; p < 12; p++) acc[p] = 0.f;
  for (int ci = 0; ci < 64; ci++){
    float xmA = xsd[ci][lane];
    float xm0 = xsd[ci][lane + 1];
    float xmB = xsd[ci][lane + 2];
    const float* wci = wsh + ci * 100 + w;
    acc[0] += wci[0] * xmA;
    acc[0] += wci[12 * 4] * xm0;
    acc[0] += wci[24 * 4] * xmB;
    #pragma unroll
    for (int p = 1; p < 12; p++){
      acc[p] += wci[(12 - p) * 4] * xm0;
      acc[p] += wci[(24 - p) * 4] * xmB;
    }
  }
  bool full = (t0 + 768 <= TD);
  {
    float o[12];
    float s = 0.f, q = 0.f;
    #pragma unroll
    for (int p = 0; p < 12; p++){
      int t = t0 + lane * 12 + p;
      float a = acc[p];
      float v = (t < TD) ? a / (1.f + expf(-a)) : 0.f;
      o[p] = v; s += v; q += v * v;
    }
    float* dst = &g_yd1[(b * 64 + cb + w) * TD + t0 + lane * 12];
    if (full){
      ((float4*)dst)[0] = make_float4(o[0], o[1], o[2], o[3]);
      ((float4*)dst)[1] = make_float4(o[4], o[5], o[6], o[7]);
      ((float4*)dst)[2] = make_float4(o[8], o[9], o[10], o[11]);
    } else {
      #pragma unroll
      for (int p = 0; p < 12; p++){
        int t = t0 + lane * 12 + p;
        if (t < TD) dst[p] = o[p];
      }
    }
    s = wsum(s); q = wsum(q);
    if (lane == 0){ atomicAdd(&sacc[w], s); atomicAdd(&qacc[w], q); }
  }
  __syncthreads();
  if (tid < 4){
    atomicAdd(&g_st[384 + (cb + tid) * 2], (double)sacc[tid]);
    atomicAdd(&g_st[384 + (cb + tid) * 2 + 1], (double)qacc[tid]);
  }
}

// ---------------- bn_d1 factors + raw dw2 transpose ----------------
__global__ void k_foldd2(const float* __restrict__ dg1, const float* __restrict__ dbe1,
                         const float* __restrict__ dw2, const float* __restrict__ db2){
  int tid = threadIdx.x;
  if (blockIdx.x == 0 && tid < 64){
    double m = g_st[384 + tid * 2] / 191912.0, v = g_st[384 + tid * 2 + 1] / 191912.0 - m * m;
    float sc = dg1[tid] / sqrtf((float)v + 1e-5f);
    g_sd1[tid] = sc; g_shd1[tid] = dbe1[tid] - (float)m * sc;
    g_db2f[tid] = db2[tid];
  }
  int gt = blockIdx.x * 256 + tid;
  for (int i = gt; i < 64 * 5 * 64; i += 32 * 256){
    int co = i & 63, r = i >> 6, k = r % 5, ci = r / 5;
    g_dw2f[i] = dw2[(co * 64 + ci) * 5 + k];
  }
}

// ---------------- dconv2: t-tile 384, 16co/wave x 6t/lane, global weights (amortize weight stream) ----------------
__global__ void __launch_bounds__(256) k_dconv2(){
  __shared__ float xs[32][388];            // 48.5 KB
  __shared__ float sdl[64], shdl[64];
  __shared__ float sacc[64], qacc[64];
  int tid = threadIdx.x, b = blockIdx.y, t0 = blockIdx.x * 384;
  int lane = tid & 63, wv = tid >> 6;
  int cb = wv * 16;
  if (tid < 64){ sdl[tid] = g_sd1[tid]; shdl[tid] = g_shd1[tid]; sacc[tid] = 0.f; qacc[tid] = 0.f; }
  float acc[6][16];
  #pragma unroll
  for (int j = 0; j < 6; j++)
    #pragma unroll
    for (int i = 0; i < 16; i++) acc[j][i] = g_db2f[cb + i];
  for (int half = 0; half < 2; ++half){
    __syncthreads();
    for (int i = tid; i < 32 * 388; i += 256){
      int ci = i / 388, tt = i - ci * 388, g = t0 - 2 + tt;
      int cia = half * 32 + ci;
      xs[ci][tt] = ((unsigned)g < TD) ? (sdl[cia] * g_yd1[(b * 64 + cia) * TD + g] + shdl[cia]) : 0.f;
    }
    __syncthreads();
    for (int ci = 0; ci < 32; ci++){
      int cia = half * 32 + ci;
      #pragma unroll
      for (int k = 0; k < 5; k++){
        const float4* wp = (const float4*)(g_dw2f + (cia * 5 + k) * 64 + cb);
        float4 w0 = wp[0], w1 = wp[1], w2v = wp[2], w3v = wp[3];
        float wr[16] = { w0.x, w0.y, w0.z, w0.w, w1.x, w1.y, w1.z, w1.w,
                         w2v.x, w2v.y, w2v.z, w2v.w, w3v.x, w3v.y, w3v.z, w3v.w };
        #pragma unroll
        for (int j = 0; j < 6; j++){
          float xv = xs[ci][lane + 64 * j + k];
          #pragma unroll
          for (int i = 0; i < 16; i++) acc[j][i] += wr[i] * xv;
        }
      }
    }
  }
  #pragma unroll
  for (int i = 0; i < 16; i++){
    int co = cb + i;
    float s = 0.f, q = 0.f;
    #pragma unroll
    for (int j = 0; j < 6; j++){
      int t = t0 + lane + 64 * j;
      bool ok = t < TD;
      float a = acc[j][i];
      float o = ok ? a / (1.f + expf(-a)) : 0.f;
      if (ok) g_yd2[(b * 64 + co) * TD + t] = o;
      s += o; q += o * o;
    }
    s = wsum(s); q = wsum(q);
    if (lane == 0){ atomicAdd(&sacc[co], s); atomicAdd(&qacc[co], q); }
  }
  __syncthreads();
  if (tid < 64){
    atomicAdd(&g_st[512 + tid * 2], (double)sacc[tid]);
    atomicAdd(&g_st[512 + tid * 2 + 1], (double)qacc[tid]);
  }
}

// ---------------- recon ----------------
__global__ void k_recon(const float* __restrict__ dg2, const float* __restrict__ dbe2,
                        const float* __restrict__ dw3, const float* __restrict__ db3,
                        float* __restrict__ outR){
  __shared__ float wf[64];
  __shared__ float bsh2;
  int tid = threadIdx.x, b = blockIdx.y, t0 = blockIdx.x * 256;
  if (tid < 64){
    double m = g_st[512 + tid * 2] / 191912.0, v = g_st[512 + tid * 2 + 1] / 191912.0 - m * m;
    float sc = dg2[tid] / sqrtf((float)v + 1e-5f);
    float shv = dbe2[tid] - (float)m * sc;
    wf[tid] = dw3[tid] * sc;
    float contrib = wsum(dw3[tid] * shv);
    if (tid == 0) bsh2 = db3[0] + contrib;
  }
  __syncthreads();
  int t = t0 + tid;
  if (t < TT){
    if (t < TD){
      float a = bsh2;
      for (int ci = 0; ci < 64; ci++) a += wf[ci] * g_yd2[(b * 64 + ci) * TD + t];
      outR[b * TT + t] = a;
    } else {
      outR[b * TT + t] = 0.f;
    }
  }
}

// ---------------- launch ----------------
extern "C" void kernel_launch(void* const* d_in, const int* in_sizes, int n_in,
                              void* d_out, int out_size, void* d_ws, size_t ws_size,
                              hipStream_t stream){
  (void)in_sizes; (void)n_in; (void)out_size; (void)d_ws; (void)ws_size;
  const float* x    = (const float*)d_in[0];
  const float* w1   = (const float*)d_in[1];
  const float* b1   = (const float*)d_in[2];
  const float* g1   = (const float*)d_in[3];
  const float* be1  = (const float*)d_in[4];
  const float* w2   = (const float*)d_in[5];
  const float* b2   = (const float*)d_in[6];
  const float* g2   = (const float*)d_in[7];
  const float* be2  = (const float*)d_in[8];
  const float* w3   = (const float*)d_in[9];
  const float* b3   = (const float*)d_in[10];
  const float* g3   = (const float*)d_in[11];
  const float* be3  = (const float*)d_in[12];
  const float* embed= (const float*)d_in[13];
  const float* dw1  = (const float*)d_in[14];
  const float* dg1  = (const float*)d_in[15];
  const float* dbe1 = (const float*)d_in[16];
  const float* dw2  = (const float*)d_in[17];
  const float* db2  = (const float*)d_in[18];
  const float* dg2  = (const float*)d_in[19];
  const float* dbe2 = (const float*)d_in[20];
  const float* dw3  = (const float*)d_in[21];
  const float* db3  = (const float*)d_in[22];
  const int* oidx   = (const int*)d_in[23];

  float* out    = (float*)d_out;
  float* outIdx = out + 192000;
  float* outS   = out + 208000;

  hipLaunchKernelGGL(k_zero, dim3(32), dim3(256), 0, stream);
  hipLaunchKernelGGL(k_embprep, dim3(64), dim3(256), 0, stream, embed);
  hipLaunchKernelGGL(k_conv1, dim3(94, 8), dim3(256), 0, stream, x, w1, b1);
  hipLaunchKernelGGL(k_fold2, dim3(8), dim3(256), 0, stream, g1, be1, w2, b2);
  hipLaunchKernelGGL(k_conv2, dim3(94, 8), dim3(256), 0, stream);
  hipLaunchKernelGGL(k_fold3, dim3(64), dim3(256), 0, stream, g2, be2, w3, b3);
  hipLaunchKernelGGL(k_conv3, dim3(63, 8), dim3(256), 0, stream);
  hipLaunchKernelGGL(k_stats, dim3(8, 64), dim3(256), 0, stream, 0, NZ, 256);
  hipLaunchKernelGGL(k_zbn, dim3(32, 8), dim3(256), 0, stream, g3, be3);
  hipLaunchKernelGGL(k_zsplit, dim3(4000), dim3(256), 0, stream);
  hipLaunchKernelGGL(k_vq1, dim3(250, 8), dim3(256), 0, stream);
  hipLaunchKernelGGL(k_vq1b, dim3(63), dim3(256), 0, stream);
  hipLaunchKernelGGL(k_vq3, dim3(4000), dim3(256), 0, stream, embed, outIdx);
  hipLaunchKernelGGL(k_orthoprep, dim3(1), dim3(256), 0, stream, embed, oidx);
  hipLaunchKernelGGL(k_ortho, dim3(64), dim3(256), 0, stream);
  hipLaunchKernelGGL(k_div, dim3(1), dim3(256), 0, stream, outS);
  hipLaunchKernelGGL(k_zq, dim3(32, 8), dim3(256), 0, stream, embed);
  hipLaunchKernelGGL(k_folddw1, dim3(100), dim3(256), 0, stream, dw1);
  hipLaunchKernelGGL(k_dconv1, dim3(32, 8, 16), dim3(256), 0, stream);
  hipLaunchKernelGGL(k_foldd2, dim3(32), dim3(256), 0, stream, dg1, dbe1, dw2, db2);
  hipLaunchKernelGGL(k_dconv2, dim3(63, 8), dim3(256), 0, stream);
  hipLaunchKernelGGL(k_recon, dim3(94, 8), dim3(256), 0, stream, dg2, dbe2, dw3, db3, out);
}